// Round 1
// baseline (5045.023 us; speedup 1.0000x reference)
//
#include <hip/hip_runtime.h>
#include <hip/hip_bf16.h>
#include <math.h>

typedef __bf16 bf16x8 __attribute__((ext_vector_type(8)));
typedef float f32x4 __attribute__((ext_vector_type(4)));

#define TOK 4096   // B*S
#define HDIM 4096
#define IDIM 11008

// ---------------------------------------------------------------------------
// 64x64 Kron transform + fake quant:  T = L^T * (X op diag) * R, per row.
// mulDiag=1: X = src*diag (activations); mulDiag=0: X = src/diag (weights,
// using L^T/R in place of inv(L)/inv(R)^T since L,R are orthonormal).
// Output: quantized integer values stored exactly as bf16, per-row scale.
// ---------------------------------------------------------------------------
__global__ __launch_bounds__(256) void t64_kernel(
    const float* __restrict__ src, const float* __restrict__ Lm,
    const float* __restrict__ Rm, const float* __restrict__ diag,
    __hip_bfloat16* __restrict__ outq, float* __restrict__ scales,
    int mulDiag, float qmax, float qlo, float qhi)
{
    __shared__ float X[64 * 68];   // stride 68: 16B-aligned rows, bank-spread
    __shared__ float M1[64 * 68];
    __shared__ float LR[64 * 68];
    const int tid = threadIdx.x;
    const int row = blockIdx.x;
    const float* srow = src + (size_t)row * 4096;

    for (int idx = tid; idx < 4096; idx += 256) {
        float d = diag[idx];
        float v = srow[idx];
        v = mulDiag ? v * d : v / d;
        X[(idx >> 6) * 68 + (idx & 63)] = v;
        LR[(idx >> 6) * 68 + (idx & 63)] = Lm[idx];
    }
    __syncthreads();

    const int p0 = (tid >> 4) << 2;
    const int j0 = (tid & 15) << 2;

    // M1 = L^T X : M1[p][j] = sum_i L[i][p] * X[i][j]
    float acc[4][4] = {};
    for (int i = 0; i < 64; ++i) {
        float a[4];
#pragma unroll
        for (int ii = 0; ii < 4; ++ii) a[ii] = LR[i * 68 + p0 + ii];
        float4 b = *(const float4*)&X[i * 68 + j0];
        float bv[4] = {b.x, b.y, b.z, b.w};
#pragma unroll
        for (int ii = 0; ii < 4; ++ii)
#pragma unroll
            for (int jj = 0; jj < 4; ++jj) acc[ii][jj] += a[ii] * bv[jj];
    }
#pragma unroll
    for (int ii = 0; ii < 4; ++ii)
        *(float4*)&M1[(p0 + ii) * 68 + j0] =
            make_float4(acc[ii][0], acc[ii][1], acc[ii][2], acc[ii][3]);
    __syncthreads();

    for (int idx = tid; idx < 4096; idx += 256)
        LR[(idx >> 6) * 68 + (idx & 63)] = Rm[idx];
    __syncthreads();

    // T = M1 R : T[p][q] = sum_j M1[p][j] * R[j][q]
    float acc2[4][4] = {};
    for (int j = 0; j < 64; ++j) {
        float a[4];
#pragma unroll
        for (int ii = 0; ii < 4; ++ii) a[ii] = M1[(p0 + ii) * 68 + j];
        float4 b = *(const float4*)&LR[j * 68 + j0];
        float bv[4] = {b.x, b.y, b.z, b.w};
#pragma unroll
        for (int ii = 0; ii < 4; ++ii)
#pragma unroll
            for (int jj = 0; jj < 4; ++jj) acc2[ii][jj] += a[ii] * bv[jj];
    }

    // row absmax reduction (reuse X, which is dead)
    float lm = 0.f;
#pragma unroll
    for (int ii = 0; ii < 4; ++ii)
#pragma unroll
        for (int jj = 0; jj < 4; ++jj) lm = fmaxf(lm, fabsf(acc2[ii][jj]));
    X[tid] = lm;
    __syncthreads();
    for (int s = 128; s > 0; s >>= 1) {
        if (tid < s) X[tid] = fmaxf(X[tid], X[tid + s]);
        __syncthreads();
    }
    const float sc = fmaxf(X[0] / qmax, 1e-8f);

#pragma unroll
    for (int ii = 0; ii < 4; ++ii)
#pragma unroll
        for (int jj = 0; jj < 4; ++jj) {
            float q = rintf(acc2[ii][jj] / sc);
            q = fminf(fmaxf(q, qlo), qhi);
            outq[(size_t)row * 4096 + (p0 + ii) * 64 + (j0 + jj)] =
                __float2bfloat16(q);
        }
    if (tid == 0) scales[row] = sc;
}

// ---------------------------------------------------------------------------
// 86x128 Kron transform + fake quant (dn branch). Dynamic LDS 158400 B.
// src may be f32 (w_down) or bf16 (h, in-place).
// ---------------------------------------------------------------------------
__global__ __launch_bounds__(512) void tdn_kernel(
    const void* __restrict__ src, int srcIsBf16,
    const float* __restrict__ Lm, const float* __restrict__ Rm,
    const float* __restrict__ diag,
    __hip_bfloat16* __restrict__ outq, float* __restrict__ scales,
    int mulDiag, float qmax, float qlo, float qhi)
{
    extern __shared__ float dsm[];
    float* X  = dsm;              // 86*132 = 11352
    float* M1 = dsm + 11352;      // 86*132
    float* LR = dsm + 22704;      // up to 128*132 = 16896
    __shared__ float red[512];

    const int tid = threadIdx.x;
    const int row = blockIdx.x;

    for (int idx = tid; idx < IDIM; idx += 512) {
        float v = srcIsBf16
            ? __bfloat162float(((const __hip_bfloat16*)src)[(size_t)row * IDIM + idx])
            : ((const float*)src)[(size_t)row * IDIM + idx];
        float d = diag[idx];
        v = mulDiag ? v * d : v / d;
        X[(idx >> 7) * 132 + (idx & 127)] = v;
    }
    for (int idx = tid; idx < 86 * 86; idx += 512) {
        int r = idx / 86, c = idx - r * 86;
        LR[r * 88 + c] = Lm[idx];     // L with stride 88
    }
    __syncthreads();

    // M1[86][128] = L^T X ; 2x4 output tiles, 43*32 = 1376 tiles
    for (int tt = tid; tt < 1376; tt += 512) {
        const int pp = (tt >> 5) * 2;
        const int jj0 = (tt & 31) * 4;
        float acc[2][4] = {};
        for (int i = 0; i < 86; ++i) {
            float a0 = LR[i * 88 + pp];
            float a1 = LR[i * 88 + pp + 1];
            float4 b = *(const float4*)&X[i * 132 + jj0];
            acc[0][0] += a0 * b.x; acc[0][1] += a0 * b.y;
            acc[0][2] += a0 * b.z; acc[0][3] += a0 * b.w;
            acc[1][0] += a1 * b.x; acc[1][1] += a1 * b.y;
            acc[1][2] += a1 * b.z; acc[1][3] += a1 * b.w;
        }
        *(float4*)&M1[pp * 132 + jj0] =
            make_float4(acc[0][0], acc[0][1], acc[0][2], acc[0][3]);
        *(float4*)&M1[(pp + 1) * 132 + jj0] =
            make_float4(acc[1][0], acc[1][1], acc[1][2], acc[1][3]);
    }
    __syncthreads();

    for (int idx = tid; idx < 128 * 128; idx += 512) {
        int r = idx >> 7, c = idx & 127;
        LR[r * 132 + c] = Rm[idx];    // R with stride 132
    }
    __syncthreads();

    // T[86][128] = M1 R, into X (dead); track absmax
    float lm = 0.f;
    for (int tt = tid; tt < 1376; tt += 512) {
        const int pp = (tt >> 5) * 2;
        const int q0 = (tt & 31) * 4;
        float acc[2][4] = {};
        for (int j = 0; j < 128; ++j) {
            float a0 = M1[pp * 132 + j];
            float a1 = M1[(pp + 1) * 132 + j];
            float4 b = *(const float4*)&LR[j * 132 + q0];
            acc[0][0] += a0 * b.x; acc[0][1] += a0 * b.y;
            acc[0][2] += a0 * b.z; acc[0][3] += a0 * b.w;
            acc[1][0] += a1 * b.x; acc[1][1] += a1 * b.y;
            acc[1][2] += a1 * b.z; acc[1][3] += a1 * b.w;
        }
        *(float4*)&X[pp * 132 + q0] =
            make_float4(acc[0][0], acc[0][1], acc[0][2], acc[0][3]);
        *(float4*)&X[(pp + 1) * 132 + q0] =
            make_float4(acc[1][0], acc[1][1], acc[1][2], acc[1][3]);
#pragma unroll
        for (int ii = 0; ii < 2; ++ii)
#pragma unroll
            for (int qq = 0; qq < 4; ++qq) lm = fmaxf(lm, fabsf(acc[ii][qq]));
    }
    red[tid] = lm;
    __syncthreads();
    for (int s = 256; s > 0; s >>= 1) {
        if (tid < s) red[tid] = fmaxf(red[tid], red[tid + s]);
        __syncthreads();
    }
    const float sc = fmaxf(red[0] / qmax, 1e-8f);

    for (int idx = tid; idx < IDIM; idx += 512) {
        float v = X[(idx >> 7) * 132 + (idx & 127)];
        float q = rintf(v / sc);
        q = fminf(fmaxf(q, qlo), qhi);
        outq[(size_t)row * IDIM + idx] = __float2bfloat16(q);
    }
    if (tid == 0) scales[row] = sc;
}

// ---------------------------------------------------------------------------
// Tiled bf16 MFMA GEMM, C = A * B^T (both row-major-K). Integer-valued bf16
// inputs -> exact integer accumulation in f32. 64x64 tile, BK=64, 4 waves.
// DUAL: two B matrices (up/gate) + SwiGLU epilogue -> bf16 h.
// SINGLE: one B + dequant epilogue -> f32 out.
// ---------------------------------------------------------------------------
template <bool DUAL>
__global__ __launch_bounds__(256) void gemm_kernel(
    const __hip_bfloat16* __restrict__ A,
    const __hip_bfloat16* __restrict__ B0,
    const __hip_bfloat16* __restrict__ B1,
    const float* __restrict__ sA,
    const float* __restrict__ sB0,
    const float* __restrict__ sB1,
    int K,
    __hip_bfloat16* __restrict__ outH,
    float* __restrict__ outF,
    int outLd)
{
    constexpr int NT = DUAL ? 3 : 2;
    __shared__ __align__(16) __hip_bfloat16 smem[NT * 64 * 72]; // 72: pad rows
    const int tid = threadIdx.x;
    const int lane15 = tid & 15;
    const int quad = (tid >> 4) & 3;
    const int wave = tid >> 6;
    const int n0 = blockIdx.x * 64;
    const int m0 = blockIdx.y * 64;

    const f32x4 zz = {0.f, 0.f, 0.f, 0.f};
    f32x4 acc0[4] = {zz, zz, zz, zz};
    f32x4 acc1[4] = {zz, zz, zz, zz};

    for (int kk = 0; kk < K; kk += 64) {
        // stage A | B0 | (B1): each thread moves 16B x 2*NT chunks
#pragma unroll
        for (int g = 0; g < 2 * NT; ++g) {
            const int tile = g >> 1;
            const int ci = ((g & 1) << 8) + tid;   // 0..511 within tile
            const int row = ci >> 3;
            const int c8 = ci & 7;
            const __hip_bfloat16* srcb =
                (tile == 0) ? A + (size_t)(m0 + row) * K
              : (tile == 1) ? B0 + (size_t)(n0 + row) * K
                            : B1 + (size_t)(n0 + row) * K;
            float4 v = *(const float4*)(srcb + kk + c8 * 8);
            *(float4*)(smem + (size_t)tile * (64 * 72) + row * 72 + c8 * 8) = v;
        }
        __syncthreads();
#pragma unroll
        for (int ks = 0; ks < 2; ++ks) {
            const int kb = ks * 32 + quad * 8;
            bf16x8 af = *(const bf16x8*)(smem + (wave * 16 + lane15) * 72 + kb);
#pragma unroll
            for (int c = 0; c < 4; ++c) {
                bf16x8 b0 = *(const bf16x8*)(smem + 64 * 72 +
                                             (c * 16 + lane15) * 72 + kb);
                acc0[c] = __builtin_amdgcn_mfma_f32_16x16x32_bf16(af, b0, acc0[c], 0, 0, 0);
                if constexpr (DUAL) {
                    bf16x8 b1 = *(const bf16x8*)(smem + 2 * 64 * 72 +
                                                 (c * 16 + lane15) * 72 + kb);
                    acc1[c] = __builtin_amdgcn_mfma_f32_16x16x32_bf16(af, b1, acc1[c], 0, 0, 0);
                }
            }
        }
        __syncthreads();
    }

    // Epilogue. D[row=quad*4+r][col=lane15] per 16x16 frag.
    const int t0 = m0 + wave * 16 + quad * 4;
    float sa[4];
#pragma unroll
    for (int r = 0; r < 4; ++r) sa[r] = sA[t0 + r];
#pragma unroll
    for (int c = 0; c < 4; ++c) {
        const int col = n0 + c * 16 + lane15;
        if constexpr (DUAL) {
            const float s0 = sB0[col], s1 = sB1[col];
#pragma unroll
            for (int r = 0; r < 4; ++r) {
                float up = acc0[c][r] * (sa[r] * s0);
                float gt = acc1[c][r] * (sa[r] * s1);
                float hv = up * (gt / (1.f + __expf(-gt)));   // silu(g)*up
                outH[(size_t)(t0 + r) * outLd + col] = __float2bfloat16(hv);
            }
        } else {
            const float s0 = sB0[col];
#pragma unroll
            for (int r = 0; r < 4; ++r)
                outF[(size_t)(t0 + r) * outLd + col] = acc0[c][r] * (sa[r] * s0);
        }
    }
}

// ---------------------------------------------------------------------------
extern "C" void kernel_launch(void* const* d_in, const int* in_sizes, int n_in,
                              void* d_out, int out_size, void* d_ws, size_t ws_size,
                              hipStream_t stream)
{
    const float* x       = (const float*)d_in[0];
    const float* w_up    = (const float*)d_in[1];
    const float* w_gate  = (const float*)d_in[2];
    const float* w_down  = (const float*)d_in[3];
    const float* up_L    = (const float*)d_in[4];
    const float* up_R    = (const float*)d_in[5];
    const float* up_diag = (const float*)d_in[6];
    const float* dn_L    = (const float*)d_in[7];
    const float* dn_R    = (const float*)d_in[8];
    const float* dn_diag = (const float*)d_in[9];
    float* out = (float*)d_out;

    char* w = (char*)d_ws;
    size_t off = 0;
    auto take = [&](size_t b) { char* p = w + off; off += (b + 255) & ~(size_t)255; return p; };
    __hip_bfloat16* wuq = (__hip_bfloat16*)take((size_t)IDIM * HDIM * 2);
    __hip_bfloat16* wgq = (__hip_bfloat16*)take((size_t)IDIM * HDIM * 2);
    __hip_bfloat16* wdq = (__hip_bfloat16*)take((size_t)HDIM * IDIM * 2);
    __hip_bfloat16* xq  = (__hip_bfloat16*)take((size_t)TOK * HDIM * 2);
    __hip_bfloat16* hq  = (__hip_bfloat16*)take((size_t)TOK * IDIM * 2);
    float* sx = (float*)take(TOK * 4);
    float* su = (float*)take(IDIM * 4);
    float* sg = (float*)take(IDIM * 4);
    float* sh = (float*)take(TOK * 4);
    float* sd = (float*)take(HDIM * 4);
    (void)in_sizes; (void)n_in; (void)out_size; (void)ws_size;

    const size_t tdn_lds = (size_t)(11352 + 11352 + 16896) * sizeof(float); // 158400
    hipFuncSetAttribute(reinterpret_cast<const void*>(&tdn_kernel),
                        hipFuncAttributeMaxDynamicSharedMemorySize, (int)tdn_lds);

    // 1) activation + weight transforms/quant
    t64_kernel<<<TOK,  256, 0, stream>>>(x,      up_L, up_R, up_diag, xq,  sx, 1, 127.f, -128.f, 127.f);
    t64_kernel<<<IDIM, 256, 0, stream>>>(w_up,   up_L, up_R, up_diag, wuq, su, 0, 7.f,   -8.f,   7.f);
    t64_kernel<<<IDIM, 256, 0, stream>>>(w_gate, up_L, up_R, up_diag, wgq, sg, 0, 7.f,   -8.f,   7.f);
    tdn_kernel<<<HDIM, 512, tdn_lds, stream>>>(w_down, 0, dn_L, dn_R, dn_diag, wdq, sd, 0, 7.f, -8.f, 7.f);

    // 2) fused up/gate GEMM + SwiGLU -> h (bf16)
    gemm_kernel<true><<<dim3(IDIM / 64, TOK / 64), 256, 0, stream>>>(
        xq, wuq, wgq, sx, su, sg, HDIM, hq, nullptr, IDIM);

    // 3) dn transform + quant of h (in place)
    tdn_kernel<<<TOK, 512, tdn_lds, stream>>>(hq, 1, dn_L, dn_R, dn_diag, hq, sh, 1, 127.f, -128.f, 127.f);

    // 4) down GEMM -> f32 output
    gemm_kernel<false><<<dim3(HDIM / 64, TOK / 64), 256, 0, stream>>>(
        hq, wdq, nullptr, sh, sd, nullptr, IDIM, nullptr, out, HDIM);
}